// Round 4
// baseline (189.264 us; speedup 1.0000x reference)
//
#include <hip/hip_runtime.h>

#define DD 256      // embed dim
#define NH 8        // heads
#define NP 1024     // patches
#define NQ 64       // query embeddings
#define SCALE 0.17677669529663687f

__device__ __forceinline__ float wred_sum(float p) {
  #pragma unroll
  for (int m = 32; m; m >>= 1) p += __shfl_xor(p, m);
  return p;
}
__device__ __forceinline__ float wred_max(float p) {
  #pragma unroll
  for (int m = 32; m; m >>= 1) p = fmaxf(p, __shfl_xor(p, m));
  return p;
}
__device__ __forceinline__ float red8(float p) {
  p += __shfl_xor(p, 1);
  p += __shfl_xor(p, 2);
  p += __shfl_xor(p, 4);
  return p;
}
__device__ __forceinline__ float dot4(float4 a, float4 b) {
  return a.x*b.x + a.y*b.y + a.z*b.z + a.w*b.w;
}
__device__ __forceinline__ void preload8(const float* x, int lane, float4* xf) {
  const int o = (lane & 7) * 4;
  #pragma unroll
  for (int cc = 0; cc < 8; ++cc) xf[cc] = *(const float4*)&x[cc*32 + o];
}
// 16 rows per pass: rows r0+(lane>>3) and r0+8+(lane>>3); 16 dwordx4 in flight.
__device__ __forceinline__ void pass16(const float* __restrict__ W, int ldk,
                                       int r0, int lane, const float4* xf,
                                       float* outA, float* outB) {
  const float* baseA = W + (size_t)(r0 + (lane >> 3))*ldk + (lane & 7)*4;
  const float* baseB = baseA + (size_t)8*ldk;
  float4 wa[8], wb[8];
  #pragma unroll
  for (int cc = 0; cc < 8; ++cc) wa[cc] = *(const float4*)&baseA[cc*32];
  #pragma unroll
  for (int cc = 0; cc < 8; ++cc) wb[cc] = *(const float4*)&baseB[cc*32];
  float a = 0.f, b = 0.f;
  #pragma unroll
  for (int cc = 0; cc < 8; ++cc) { a += dot4(wa[cc], xf[cc]); b += dot4(wb[cc], xf[cc]); }
  *outA = red8(a); *outB = red8(b);
}

// layernorm over a 256-float LDS buffer -> outp (LDS or global); any block size >=256
__device__ __forceinline__ void layernorm_store(const float* buf, float* outp,
                                                const float* g, const float* b,
                                                float* red, int tid, int wid, int lane)
{
  __syncthreads();
  if (wid == 0) {
    float s = buf[lane] + buf[lane+64] + buf[lane+128] + buf[lane+192];
    s = wred_sum(s);
    if (!lane) red[0] = s * (1.f/256.f);
  }
  __syncthreads();
  float mn = red[0];
  if (wid == 0) {
    float d0 = buf[lane]-mn, d1 = buf[lane+64]-mn, d2 = buf[lane+128]-mn, d3 = buf[lane+192]-mn;
    float s = d0*d0 + d1*d1 + d2*d2 + d3*d3;
    s = wred_sum(s);
    if (!lane) red[1] = rsqrtf(s * (1.f/256.f) + 1e-5f);
  }
  __syncthreads();
  if (tid < 256) outp[tid] = (buf[tid] - mn) * red[1] * g[tid] + b[tid];
}

// ---------------- patches transpose ----------------
__global__ __launch_bounds__(256)
void k_transpose(const float* __restrict__ in, float* __restrict__ out)
{
  __shared__ float tile[32][33];
  const int pb = blockIdx.x*32, cb = blockIdx.y*32;
  const int tx = threadIdx.x, ty = threadIdx.y;
  #pragma unroll
  for (int i = 0; i < 4; ++i)
    tile[ty + i*8][tx] = in[(size_t)(pb + ty + i*8)*DD + cb + tx];
  __syncthreads();
  #pragma unroll
  for (int i = 0; i < 4; ++i)
    out[(size_t)(cb + ty + i*8)*NP + pb + tx] = tile[tx][ty + i*8];
}

// ---------------- K/V projection of query_embeddings ----------------
__global__ __launch_bounds__(512)
void k_kvq(const float* __restrict__ qe, const float* __restrict__ Wqkv_q,
           const float* __restrict__ bqkv_q, float* __restrict__ kvq)
{
  const int j = blockIdx.x, tid = threadIdx.x, w = tid>>6, lane = tid&63;
  __shared__ float x[DD], kvrow[512];
  if (tid < DD) x[tid] = qe[j*DD + tid];
  __syncthreads();
  float4 xf[8]; preload8(x, lane, xf);
  #pragma unroll
  for (int g = 0; g < 4; ++g) {
    int r0 = w*64 + g*16;
    float a, b;
    pass16(Wqkv_q + (size_t)DD*DD, DD, r0, lane, xf, &a, &b);
    int rA = r0 + (lane >> 3);
    if ((lane & 7) == 0) { kvrow[rA] = a + bqkv_q[DD + rA]; kvrow[rA+8] = b + bqkv_q[DD + rA + 8]; }
  }
  __syncthreads();
  kvq[(size_t)j*512 + tid] = kvrow[tid];
}

// ---------------- q projection + t = q_h^T Wk_h (streams Wq, Wk) ----------------
__global__ __launch_bounds__(1024)
void k_qt(const float* __restrict__ et_g, const float* __restrict__ Wqkv,
          const float* __restrict__ bqkv, float* __restrict__ t_ws)
{
  const int n = blockIdx.x, tid = threadIdx.x, w = tid>>6, lane = tid&63;
  __shared__ float xL[DD], qL[DD], tpart[2][NH][DD];
  if (tid < DD) xL[tid] = et_g[n*DD + tid];
  __syncthreads();
  const float* Wn = Wqkv + (size_t)n*(3*DD*DD);
  const float* bn = bqkv + (size_t)n*(3*DD);
  // q-phase: wave w -> rows [w*16, w*16+16)
  {
    float4 xf[8]; preload8(xL, lane, xf);
    float a, b;
    pass16(Wn, DD, w*16, lane, xf, &a, &b);
    int rA = w*16 + (lane >> 3);
    if ((lane & 7) == 0) { qL[rA] = a + bn[rA]; qL[rA+8] = b + bn[rA+8]; }
  }
  // t-phase: wave w -> head w>>1, k-half w&1 (reads exactly the qL rows this wave wrote)
  {
    const int h = w >> 1, kh = w & 1;
    const float* Wk = Wn + (size_t)DD*DD + (size_t)(h*32 + kh*16)*DD;
    float4 acc = make_float4(0.f,0.f,0.f,0.f);
    #pragma unroll
    for (int dc = 0; dc < 4; ++dc) {
      float4 q4 = *(const float4*)&qL[h*32 + kh*16 + dc*4];
      float4 r0v = *(const float4*)&Wk[(size_t)(dc*4+0)*DD + 4*lane];
      float4 r1v = *(const float4*)&Wk[(size_t)(dc*4+1)*DD + 4*lane];
      float4 r2v = *(const float4*)&Wk[(size_t)(dc*4+2)*DD + 4*lane];
      float4 r3v = *(const float4*)&Wk[(size_t)(dc*4+3)*DD + 4*lane];
      acc.x += q4.x*r0v.x + q4.y*r1v.x + q4.z*r2v.x + q4.w*r3v.x;
      acc.y += q4.x*r0v.y + q4.y*r1v.y + q4.z*r2v.y + q4.w*r3v.y;
      acc.z += q4.x*r0v.z + q4.y*r1v.z + q4.z*r2v.z + q4.w*r3v.z;
      acc.w += q4.x*r0v.w + q4.y*r1v.w + q4.z*r2v.w + q4.w*r3v.w;
    }
    *(float4*)&tpart[kh][h][4*lane] = acc;
  }
  __syncthreads();
  if (tid < 512) {
    float4 a = ((const float4*)&tpart[0][0][0])[tid];
    float4 b = ((const float4*)&tpart[1][0][0])[tid];
    float4 o = make_float4(a.x+b.x, a.y+b.y, a.z+b.z, a.w+b.w);
    *(float4*)&t_ws[(size_t)n*2048 + 4*tid] = o;
  }
}

// ---------------- scores + softmax + iaw + u ----------------
__global__ __launch_bounds__(1024)
void k_scores(const float* __restrict__ pT, const float* __restrict__ patches,
              const float* __restrict__ t_ws, float* __restrict__ u_ws,
              float* __restrict__ iaw)
{
  const int n = blockIdx.x, tid = threadIdx.x, w = tid>>6, lane = tid&63;
  __shared__ float tS[NH][DD];       // 8 KB
  __shared__ float attS[NH][NP];     // 32 KB
  __shared__ float up[4][NH][DD];    // 32 KB
  if (tid < 512) ((float4*)&tS[0][0])[tid] = ((const float4*)(t_ws + (size_t)n*2048))[tid];
  __syncthreads();
  // S-phase: thread owns patch tid
  {
    float acc[NH];
    #pragma unroll
    for (int h = 0; h < NH; ++h) acc[h] = 0.f;
    #pragma unroll 2
    for (int c4 = 0; c4 < 64; ++c4) {
      float p0 = pT[(size_t)(c4*4+0)*NP + tid];
      float p1 = pT[(size_t)(c4*4+1)*NP + tid];
      float p2 = pT[(size_t)(c4*4+2)*NP + tid];
      float p3 = pT[(size_t)(c4*4+3)*NP + tid];
      #pragma unroll
      for (int h = 0; h < NH; ++h) {
        float4 t4 = *(const float4*)&tS[h][c4*4];
        acc[h] += t4.x*p0 + t4.y*p1 + t4.z*p2 + t4.w*p3;
      }
    }
    #pragma unroll
    for (int h = 0; h < NH; ++h) attS[h][tid] = acc[h];
  }
  __syncthreads();
  // softmax (waves 0-7, wave == head), store normalized probabilities
  if (w < 8) {
    const int h = w;
    float v[16];
    #pragma unroll
    for (int k = 0; k < 16; ++k) v[k] = attS[h][k*64 + lane] * SCALE;
    float mx = v[0];
    #pragma unroll
    for (int k = 1; k < 16; ++k) mx = fmaxf(mx, v[k]);
    mx = wred_max(mx);
    float sum = 0.f;
    #pragma unroll
    for (int k = 0; k < 16; ++k) { v[k] = __expf(v[k] - mx); sum += v[k]; }
    sum = wred_sum(sum);
    float rinv = 1.f / sum;
    #pragma unroll
    for (int k = 0; k < 16; ++k) attS[h][k*64 + lane] = v[k] * rinv;
  }
  __syncthreads();
  // iaw: head-mean (thread owns patch tid)
  {
    float s = 0.f;
    #pragma unroll
    for (int h = 0; h < NH; ++h) s += attS[h][tid];
    iaw[(size_t)n*NP + tid] = s * 0.125f;
  }
  // u-phase: 4-way split-k over patch quarters; 4 waves cover 256 cols
  {
    const int ph = w >> 2, c = (w & 3)*64 + lane;
    float ua[NH];
    #pragma unroll
    for (int h = 0; h < NH; ++h) ua[h] = 0.f;
    const float* pb = patches + (size_t)ph*256*DD + c;
    #pragma unroll 2
    for (int pc = 0; pc < 64; ++pc) {
      float p0 = pb[(size_t)(pc*4+0)*DD];
      float p1 = pb[(size_t)(pc*4+1)*DD];
      float p2 = pb[(size_t)(pc*4+2)*DD];
      float p3 = pb[(size_t)(pc*4+3)*DD];
      #pragma unroll
      for (int h = 0; h < NH; ++h) {
        float4 a4 = *(const float4*)&attS[h][ph*256 + pc*4];
        ua[h] += a4.x*p0 + a4.y*p1 + a4.z*p2 + a4.w*p3;
      }
    }
    #pragma unroll
    for (int h = 0; h < NH; ++h) up[ph][h][c] = ua[h];
  }
  __syncthreads();
  if (tid < DD) {
    #pragma unroll
    for (int h = 0; h < NH; ++h)
      u_ws[(size_t)n*2048 + h*256 + tid] =
        up[0][h][tid] + up[1][h][tid] + up[2][h][tid] + up[3][h][tid];
  }
}

// ---------------- ctx = u @ Wv^T + bv ; out = ctx @ Wo^T + bo + et ; LN1 ----------------
__global__ __launch_bounds__(1024)
void k_ctxout(const float* __restrict__ u_ws, const float* __restrict__ et_g,
              const float* __restrict__ Wqkv, const float* __restrict__ bqkv,
              const float* __restrict__ Wo, const float* __restrict__ bo,
              const float* __restrict__ ln1g, const float* __restrict__ ln1b,
              float* __restrict__ aln)
{
  const int n = blockIdx.x, tid = threadIdx.x, w = tid>>6, lane = tid&63;
  __shared__ float uL[NH][DD], ctxL[DD], resS[DD], red2[2];
  if (tid < 512) ((float4*)&uL[0][0])[tid] = ((const float4*)(u_ws + (size_t)n*2048))[tid];
  __syncthreads();
  const float* Wn = Wqkv + (size_t)n*(3*DD*DD);
  const float* bn = bqkv + (size_t)n*(3*DD);
  // ctx: wave w -> rows [w*16, +16), head w>>1
  {
    float4 xf[8]; preload8(&uL[w >> 1][0], lane, xf);
    float a, b;
    pass16(Wn + (size_t)2*DD*DD, DD, w*16, lane, xf, &a, &b);
    int rA = w*16 + (lane >> 3);
    if ((lane & 7) == 0) { ctxL[rA] = a + bn[2*DD + rA]; ctxL[rA+8] = b + bn[2*DD + rA + 8]; }
  }
  __syncthreads();
  // out proj + residual
  {
    float4 xf[8]; preload8(ctxL, lane, xf);
    const float* Won = Wo + (size_t)n*DD*DD;
    float a, b;
    pass16(Won, DD, w*16, lane, xf, &a, &b);
    int rA = w*16 + (lane >> 3);
    if ((lane & 7) == 0) {
      resS[rA]   = a + bo[n*DD + rA]     + et_g[(size_t)n*DD + rA];
      resS[rA+8] = b + bo[n*DD + rA + 8] + et_g[(size_t)n*DD + rA + 8];
    }
  }
  layernorm_store(resS, aln + (size_t)n*DD, ln1g, ln1b, red2, tid, w, lane);
}

// ---------------- tail: qca + LN2 + FFN + qkv_s projection ----------------
__global__ __launch_bounds__(1024)
void k_tail(const float* __restrict__ aln, const float* __restrict__ kvq,
            const float* __restrict__ Wqkv_q, const float* __restrict__ bqkv_q,
            const float* __restrict__ Wo_q, const float* __restrict__ bo_q,
            const float* __restrict__ W1, const float* __restrict__ b1,
            const float* __restrict__ W2, const float* __restrict__ b2,
            const float* __restrict__ Wqkv_s, const float* __restrict__ bqkv_s,
            const float* __restrict__ ln2g, const float* __restrict__ ln2b,
            float* __restrict__ er_g, float* __restrict__ qkvs_g)
{
  const int i = blockIdx.x, tid = threadIdx.x, w = tid>>6, lane = tid&63;
  __shared__ float xL[DD], qv[DD], attq[NH][NQ], ctxS[DD], resS[DD], red2[2];
  __shared__ float hb[1024], qrow[768];
  if (tid < DD) xL[tid] = aln[(size_t)i*DD + tid];
  __syncthreads();
  // q projection: wave w -> rows w*16
  {
    float4 xf[8]; preload8(xL, lane, xf);
    float a, b;
    pass16(Wqkv_q, DD, w*16, lane, xf, &a, &b);
    int rA = w*16 + (lane >> 3);
    if ((lane & 7) == 0) { qv[rA] = a + bqkv_q[rA]; qv[rA+8] = b + bqkv_q[rA+8]; }
  }
  __syncthreads();
  // attention over 64 kv (waves 0-7: wave == head, lane == j)
  if (w < 8) {
    const int h = w, j = lane;
    float4 q4[8];
    #pragma unroll
    for (int m = 0; m < 8; ++m) q4[m] = *(const float4*)&qv[h*32 + 4*m];
    const float* kj = kvq + (size_t)j*512 + h*32;
    float s = 0.f;
    #pragma unroll
    for (int m = 0; m < 8; ++m) s += dot4(*(const float4*)&kj[4*m], q4[m]);
    s *= SCALE;
    float mx = wred_max(s);
    float p = __expf(s - mx);
    float sum = wred_sum(p);
    attq[h][j] = p / sum;
  }
  __syncthreads();
  if (tid < DD) {
    const int rr = tid, h = rr >> 5;
    float acc = 0.f;
    #pragma unroll 4
    for (int j4 = 0; j4 < 16; ++j4) {
      float4 a4 = *(const float4*)&attq[h][j4*4];
      acc += a4.x * kvq[(size_t)(j4*4+0)*512 + DD + rr]
           + a4.y * kvq[(size_t)(j4*4+1)*512 + DD + rr]
           + a4.z * kvq[(size_t)(j4*4+2)*512 + DD + rr]
           + a4.w * kvq[(size_t)(j4*4+3)*512 + DD + rr];
    }
    ctxS[rr] = acc;
  }
  __syncthreads();
  // out proj + residual + LN2 -> xL
  {
    float4 xf[8]; preload8(ctxS, lane, xf);
    float a, b;
    pass16(Wo_q, DD, w*16, lane, xf, &a, &b);
    int rA = w*16 + (lane >> 3);
    if ((lane & 7) == 0) { resS[rA] = a + bo_q[rA] + xL[rA]; resS[rA+8] = b + bo_q[rA+8] + xL[rA+8]; }
  }
  layernorm_store(resS, xL, ln2g, ln2b, red2, tid, w, lane);
  __syncthreads();
  // FFN1: wave w -> rows [w*64, +64)
  {
    float4 xf[8]; preload8(xL, lane, xf);
    #pragma unroll
    for (int g = 0; g < 4; ++g) {
      int r0 = w*64 + g*16;
      float a, b;
      pass16(W1, DD, r0, lane, xf, &a, &b);
      int rA = r0 + (lane >> 3);
      if ((lane & 7) == 0) { hb[rA] = fmaxf(a + b1[rA], 0.f); hb[rA+8] = fmaxf(b + b1[rA+8], 0.f); }
    }
  }
  __syncthreads();
  // FFN2 (K = 1024 in 4 chunks): wave w -> rows w*16
  {
    float accA = 0.f, accB = 0.f;
    #pragma unroll
    for (int kc = 0; kc < 4; ++kc) {
      float4 xh[8]; preload8(hb + kc*256, lane, xh);
      float a, b;
      pass16(W2 + kc*256, 1024, w*16, lane, xh, &a, &b);
      accA += a; accB += b;
    }
    int rA = w*16 + (lane >> 3);
    if ((lane & 7) == 0) { qv[rA] = accA + b2[rA]; qv[rA+8] = accB + b2[rA+8]; }
  }
  __syncthreads();
  // qkv_s projection (768 rows): wave w -> rows [w*48, +48)
  {
    float4 xf[8]; preload8(qv, lane, xf);
    #pragma unroll
    for (int g = 0; g < 3; ++g) {
      int r0 = w*48 + g*16;
      float a, b;
      pass16(Wqkv_s, DD, r0, lane, xf, &a, &b);
      int rA = r0 + (lane >> 3);
      if ((lane & 7) == 0) { qrow[rA] = a + bqkv_s[rA]; qrow[rA+8] = b + bqkv_s[rA+8]; }
    }
  }
  __syncthreads();
  if (tid < 768) qkvs_g[(size_t)i*768 + tid] = qrow[tid];
  if (tid < DD) er_g[(size_t)i*DD + tid] = qv[tid];
}

// ---------------- self attention + LN3 ----------------
__global__ __launch_bounds__(1024)
void k_sa(const float* __restrict__ er, const float* __restrict__ qkvs,
          const float* __restrict__ Wo_s, const float* __restrict__ bo_s,
          const float* __restrict__ ln3g, const float* __restrict__ ln3b,
          float* __restrict__ ef)
{
  const int i = blockIdx.x, tid = threadIdx.x, w = tid >> 6, lane = tid & 63;
  __shared__ float x[DD], attl[NH][256], ctxp[4][DD], resS[DD], red2[2];
  if (tid < DD) x[tid] = er[(size_t)i*DD + tid];
  // scores: wave w -> head w&7, key-half w>>3 (2 reps of 64 keys)
  {
    const int h = w & 7, kh = w >> 3;
    float4 q4[8];
    #pragma unroll
    for (int m = 0; m < 8; ++m) q4[m] = *(const float4*)&qkvs[(size_t)i*768 + h*32 + 4*m];
    #pragma unroll
    for (int rep = 0; rep < 2; ++rep) {
      int j = kh*128 + rep*64 + lane;
      const float* kj = qkvs + (size_t)j*768 + DD + h*32;
      float4 k4[8];
      #pragma unroll
      for (int m = 0; m < 8; ++m) k4[m] = *(const float4*)&kj[4*m];
      float s = 0.f;
      #pragma unroll
      for (int m = 0; m < 8; ++m) s += dot4(k4[m], q4[m]);
      attl[h][j] = s * SCALE;
    }
  }
  __syncthreads();
  // softmax over 256 keys (waves 0-7)
  if (w < 8) {
    const int h = w;
    float v0 = attl[h][lane], v1 = attl[h][lane+64], v2 = attl[h][lane+128], v3 = attl[h][lane+192];
    float mx = wred_max(fmaxf(fmaxf(v0,v1), fmaxf(v2,v3)));
    float e0 = __expf(v0-mx), e1 = __expf(v1-mx), e2 = __expf(v2-mx), e3 = __expf(v3-mx);
    float sum = wred_sum(e0+e1+e2+e3);
    float r = 1.f/sum;
    attl[h][lane] = e0*r; attl[h][lane+64] = e1*r; attl[h][lane+128] = e2*r; attl[h][lane+192] = e3*r;
  }
  __syncthreads();
  // ctx: 4-way split-k over key quarters
  {
    const int rr = tid & 255, qtr = tid >> 8, h = rr >> 5;
    float acc = 0.f;
    #pragma unroll 4
    for (int j4 = qtr*16; j4 < qtr*16 + 16; ++j4) {
      float4 a4 = *(const float4*)&attl[h][j4*4];
      acc += a4.x * qkvs[(size_t)(j4*4+0)*768 + 512 + rr]
           + a4.y * qkvs[(size_t)(j4*4+1)*768 + 512 + rr]
           + a4.z * qkvs[(size_t)(j4*4+2)*768 + 512 + rr]
           + a4.w * qkvs[(size_t)(j4*4+3)*768 + 512 + rr];
    }
    ctxp[qtr][rr] = acc;
  }
  __syncthreads();
  // out proj + residual + LN3
  {
    float4 xf[8];
    const int o = (lane & 7)*4;
    #pragma unroll
    for (int cc = 0; cc < 8; ++cc) {
      float4 a = *(const float4*)&ctxp[0][cc*32 + o];
      float4 b = *(const float4*)&ctxp[1][cc*32 + o];
      float4 c = *(const float4*)&ctxp[2][cc*32 + o];
      float4 d = *(const float4*)&ctxp[3][cc*32 + o];
      xf[cc] = make_float4(a.x+b.x+c.x+d.x, a.y+b.y+c.y+d.y,
                           a.z+b.z+c.z+d.z, a.w+b.w+c.w+d.w);
    }
    float a, b;
    pass16(Wo_s, DD, w*16, lane, xf, &a, &b);
    int rA = w*16 + (lane >> 3);
    if ((lane & 7) == 0) { resS[rA] = a + bo_s[rA] + x[rA]; resS[rA+8] = b + bo_s[rA+8] + x[rA+8]; }
  }
  layernorm_store(resS, ef + (size_t)i*DD, ln3g, ln3b, red2, tid, w, lane);
}

extern "C" void kernel_launch(void* const* d_in, const int* in_sizes, int n_in,
                              void* d_out, int out_size, void* d_ws, size_t ws_size,
                              hipStream_t stream) {
  const float* patches = (const float*)d_in[0];
  const float* et      = (const float*)d_in[1];
  const float* qe      = (const float*)d_in[2];
  const float* Wqkv_e  = (const float*)d_in[3];
  const float* bqkv_e  = (const float*)d_in[4];
  const float* Wo_e    = (const float*)d_in[5];
  const float* bo_e    = (const float*)d_in[6];
  const float* Wqkv_q  = (const float*)d_in[7];
  const float* bqkv_q  = (const float*)d_in[8];
  const float* Wo_q    = (const float*)d_in[9];
  const float* bo_q    = (const float*)d_in[10];
  const float* Wqkv_s  = (const float*)d_in[11];
  const float* bqkv_s  = (const float*)d_in[12];
  const float* Wo_s    = (const float*)d_in[13];
  const float* bo_s    = (const float*)d_in[14];
  const float* W1      = (const float*)d_in[15];
  const float* b1      = (const float*)d_in[16];
  const float* W2      = (const float*)d_in[17];
  const float* b2      = (const float*)d_in[18];
  const float* ln1g = (const float*)d_in[19]; const float* ln1b = (const float*)d_in[20];
  const float* ln2g = (const float*)d_in[21]; const float* ln2b = (const float*)d_in[22];
  const float* ln3g = (const float*)d_in[23]; const float* ln3b = (const float*)d_in[24];

  float* ef  = (float*)d_out;
  float* iaw = (float*)d_out + 65536;

  float* ws   = (float*)d_ws;
  float* pT   = ws;                   // 262144 floats
  float* kvq  = ws + 262144;          // 32768
  float* t_u  = ws + 294912;          // 524288 (t, later aliased as u)
  float* aln  = ws + 819200;          // 65536
  float* er   = ws + 884736;          // 65536
  float* qkvs = ws + 950272;          // 196608

  k_transpose<<<dim3(32, 8), dim3(32, 8), 0, stream>>>(patches, pT);
  k_kvq<<<64, 512, 0, stream>>>(qe, Wqkv_q, bqkv_q, kvq);
  k_qt<<<256, 1024, 0, stream>>>(et, Wqkv_e, bqkv_e, t_u);
  k_scores<<<256, 1024, 0, stream>>>(pT, patches, t_u, t_u, iaw);
  k_ctxout<<<256, 1024, 0, stream>>>(t_u, et, Wqkv_e, bqkv_e, Wo_e, bo_e, ln1g, ln1b, aln);
  k_tail<<<256, 1024, 0, stream>>>(aln, kvq, Wqkv_q, bqkv_q, Wo_q, bo_q,
                                   W1, b1, W2, b2, Wqkv_s, bqkv_s, ln2g, ln2b, er, qkvs);
  k_sa<<<256, 1024, 0, stream>>>(er, qkvs, Wo_s, bo_s, ln3g, ln3b, ef);
}

// Round 5
// 183.197 us; speedup vs baseline: 1.0331x; 1.0331x over previous
//
#include <hip/hip_runtime.h>

#define DD 256      // embed dim
#define NH 8        // heads
#define NP 1024     // patches
#define NQ 64       // query embeddings
#define SCALE 0.17677669529663687f

__device__ __forceinline__ float wred_sum(float p) {
  #pragma unroll
  for (int m = 32; m; m >>= 1) p += __shfl_xor(p, m);
  return p;
}
__device__ __forceinline__ float wred_max(float p) {
  #pragma unroll
  for (int m = 32; m; m >>= 1) p = fmaxf(p, __shfl_xor(p, m));
  return p;
}
__device__ __forceinline__ float red8(float p) {
  p += __shfl_xor(p, 1);
  p += __shfl_xor(p, 2);
  p += __shfl_xor(p, 4);
  return p;
}
__device__ __forceinline__ float dot4(float4 a, float4 b) {
  return a.x*b.x + a.y*b.y + a.z*b.z + a.w*b.w;
}
__device__ __forceinline__ void preload8(const float* x, int lane, float4* xf) {
  const int o = (lane & 7) * 4;
  #pragma unroll
  for (int cc = 0; cc < 8; ++cc) xf[cc] = *(const float4*)&x[cc*32 + o];
}
// 16 rows per pass: rows r0+(lane>>3) and r0+8+(lane>>3); 16 dwordx4 in flight.
__device__ __forceinline__ void pass16(const float* __restrict__ W, int ldk,
                                       int r0, int lane, const float4* xf,
                                       float* outA, float* outB) {
  const float* baseA = W + (size_t)(r0 + (lane >> 3))*ldk + (lane & 7)*4;
  const float* baseB = baseA + (size_t)8*ldk;
  float4 wa[8], wb[8];
  #pragma unroll
  for (int cc = 0; cc < 8; ++cc) wa[cc] = *(const float4*)&baseA[cc*32];
  #pragma unroll
  for (int cc = 0; cc < 8; ++cc) wb[cc] = *(const float4*)&baseB[cc*32];
  float a = 0.f, b = 0.f;
  #pragma unroll
  for (int cc = 0; cc < 8; ++cc) { a += dot4(wa[cc], xf[cc]); b += dot4(wb[cc], xf[cc]); }
  *outA = red8(a); *outB = red8(b);
}

// layernorm over a 256-float LDS buffer -> outp; caller must __syncthreads() after.
__device__ __forceinline__ void layernorm_store(const float* buf, float* outp,
                                                const float* g, const float* b,
                                                float* red, int tid, int wid, int lane)
{
  __syncthreads();
  if (wid == 0) {
    float s = buf[lane] + buf[lane+64] + buf[lane+128] + buf[lane+192];
    s = wred_sum(s);
    if (!lane) red[0] = s * (1.f/256.f);
  }
  __syncthreads();
  float mn = red[0];
  if (wid == 0) {
    float d0 = buf[lane]-mn, d1 = buf[lane+64]-mn, d2 = buf[lane+128]-mn, d3 = buf[lane+192]-mn;
    float s = d0*d0 + d1*d1 + d2*d2 + d3*d3;
    s = wred_sum(s);
    if (!lane) red[1] = rsqrtf(s * (1.f/256.f) + 1e-5f);
  }
  __syncthreads();
  if (tid < 256) outp[tid] = (buf[tid] - mn) * red[1] * g[tid] + b[tid];
}

// ---------------- K1: patches transpose (blocks 0-255) + kvq (blocks 256-319) ----------------
__global__ __launch_bounds__(256)
void k_pre(const float* __restrict__ patches, float* __restrict__ pT,
           const float* __restrict__ qe, const float* __restrict__ Wqkv_q,
           const float* __restrict__ bqkv_q, float* __restrict__ kvq)
{
  const int b = blockIdx.x, tid = threadIdx.x;
  __shared__ float tile[32][33];          // transpose branch
  __shared__ float x[DD], kvrow[512];     // kvq branch
  if (b < 256) {
    const int pb = (b & 31)*32, cb = (b >> 5)*32;
    const int tx = tid & 31, ty = tid >> 5;
    #pragma unroll
    for (int i = 0; i < 4; ++i)
      tile[ty + i*8][tx] = patches[(size_t)(pb + ty + i*8)*DD + cb + tx];
    __syncthreads();
    #pragma unroll
    for (int i = 0; i < 4; ++i)
      pT[(size_t)(cb + ty + i*8)*NP + pb + tx] = tile[tx][ty + i*8];
  } else {
    const int j = b - 256, w = tid >> 6, lane = tid & 63;
    if (tid < DD) x[tid] = qe[j*DD + tid];
    __syncthreads();
    float4 xf[8]; preload8(x, lane, xf);
    #pragma unroll
    for (int g = 0; g < 8; ++g) {
      int r0 = w*128 + g*16;
      float a, bb;
      pass16(Wqkv_q + (size_t)DD*DD, DD, r0, lane, xf, &a, &bb);
      int rA = r0 + (lane >> 3);
      if ((lane & 7) == 0) {
        kvrow[rA]   = a  + bqkv_q[DD + rA];
        kvrow[rA+8] = bb + bqkv_q[DD + rA + 8];
      }
    }
    __syncthreads();
    kvq[(size_t)j*512 + tid]       = kvrow[tid];
    kvq[(size_t)j*512 + 256 + tid] = kvrow[256 + tid];
  }
}

// ---------------- K2: full per-expert pipeline (block n == expert n) ----------------
__global__ __launch_bounds__(1024)
void k_expert(const float* __restrict__ patches, const float* __restrict__ pT,
              const float* __restrict__ et_g,
              const float* __restrict__ Wqkv_e, const float* __restrict__ bqkv_e,
              const float* __restrict__ Wo_e, const float* __restrict__ bo_e,
              const float* __restrict__ kvq,
              const float* __restrict__ Wqkv_q, const float* __restrict__ bqkv_q,
              const float* __restrict__ Wo_q, const float* __restrict__ bo_q,
              const float* __restrict__ W1, const float* __restrict__ b1,
              const float* __restrict__ W2, const float* __restrict__ b2,
              const float* __restrict__ Wqkv_s, const float* __restrict__ bqkv_s,
              const float* __restrict__ ln1g, const float* __restrict__ ln1b,
              const float* __restrict__ ln2g, const float* __restrict__ ln2b,
              float* __restrict__ er_g, float* __restrict__ qkvs_g,
              float* __restrict__ iaw)
{
  const int n = blockIdx.x, tid = threadIdx.x, w = tid >> 6, lane = tid & 63;
  __shared__ float attS[NH][NP];    // 32 KB; later: hb[1024] (FFN hidden)
  __shared__ float up[4][NH][DD];   // 32 KB; first: tpart[2][8][256]; later: qrow[768]
  __shared__ float tS[NH][DD];      // 8 KB;  t, then u
  __shared__ float xL[DD], qL[DD], ctxL[DD], resS[DD], attq[NH][NQ], red2[2];

  const float* Wn = Wqkv_e + (size_t)n*(3*DD*DD);
  const float* bn = bqkv_e + (size_t)n*(3*DD);
  float (*tpart)[NH][DD] = (float(*)[NH][DD])&up[0][0][0];
  float* hb   = &attS[0][0];
  float* qrow = &up[0][0][0];

  if (tid < DD) xL[tid] = et_g[(size_t)n*DD + tid];
  __syncthreads();

  // ---- q projection (streams Wq): wave w -> rows [w*16, +16) ----
  {
    float4 xf[8]; preload8(xL, lane, xf);
    float a, b;
    pass16(Wn, DD, w*16, lane, xf, &a, &b);
    int rA = w*16 + (lane >> 3);
    if ((lane & 7) == 0) { qL[rA] = a + bn[rA]; qL[rA+8] = b + bn[rA+8]; }
  }
  // ---- t = q_h^T Wk_h (streams Wk): wave w -> head w>>1, k-half w&1 (same qL rows it wrote) ----
  {
    const int h = w >> 1, kh = w & 1;
    const float* Wk = Wn + (size_t)DD*DD + (size_t)(h*32 + kh*16)*DD;
    float4 acc = make_float4(0.f,0.f,0.f,0.f);
    #pragma unroll
    for (int dc = 0; dc < 4; ++dc) {
      float4 q4 = *(const float4*)&qL[h*32 + kh*16 + dc*4];
      float4 r0v = *(const float4*)&Wk[(size_t)(dc*4+0)*DD + 4*lane];
      float4 r1v = *(const float4*)&Wk[(size_t)(dc*4+1)*DD + 4*lane];
      float4 r2v = *(const float4*)&Wk[(size_t)(dc*4+2)*DD + 4*lane];
      float4 r3v = *(const float4*)&Wk[(size_t)(dc*4+3)*DD + 4*lane];
      acc.x += q4.x*r0v.x + q4.y*r1v.x + q4.z*r2v.x + q4.w*r3v.x;
      acc.y += q4.x*r0v.y + q4.y*r1v.y + q4.z*r2v.y + q4.w*r3v.y;
      acc.z += q4.x*r0v.z + q4.y*r1v.z + q4.z*r2v.z + q4.w*r3v.z;
      acc.w += q4.x*r0v.w + q4.y*r1v.w + q4.z*r2v.w + q4.w*r3v.w;
    }
    *(float4*)&tpart[kh][h][4*lane] = acc;
  }
  __syncthreads();
  {
    float* tf = &tS[0][0];
    const float* t0 = &tpart[0][0][0];
    const float* t1 = &tpart[1][0][0];
    #pragma unroll
    for (int idx = tid; idx < NH*DD; idx += 1024) tf[idx] = t0[idx] + t1[idx];
  }
  __syncthreads();

  // ---- scores: thread owns patch tid ----
  {
    float acc[NH];
    #pragma unroll
    for (int h = 0; h < NH; ++h) acc[h] = 0.f;
    #pragma unroll 2
    for (int c4 = 0; c4 < 64; ++c4) {
      float p0 = pT[(size_t)(c4*4+0)*NP + tid];
      float p1 = pT[(size_t)(c4*4+1)*NP + tid];
      float p2 = pT[(size_t)(c4*4+2)*NP + tid];
      float p3 = pT[(size_t)(c4*4+3)*NP + tid];
      #pragma unroll
      for (int h = 0; h < NH; ++h) {
        float4 t4 = *(const float4*)&tS[h][c4*4];
        acc[h] += t4.x*p0 + t4.y*p1 + t4.z*p2 + t4.w*p3;
      }
    }
    #pragma unroll
    for (int h = 0; h < NH; ++h) attS[h][tid] = acc[h];
  }
  __syncthreads();
  // ---- softmax (waves 0-7, wave == head) ----
  if (w < 8) {
    const int h = w;
    float v[16];
    #pragma unroll
    for (int k = 0; k < 16; ++k) v[k] = attS[h][k*64 + lane] * SCALE;
    float mx = v[0];
    #pragma unroll
    for (int k = 1; k < 16; ++k) mx = fmaxf(mx, v[k]);
    mx = wred_max(mx);
    float sum = 0.f;
    #pragma unroll
    for (int k = 0; k < 16; ++k) { v[k] = __expf(v[k] - mx); sum += v[k]; }
    sum = wred_sum(sum);
    float rinv = 1.f / sum;
    #pragma unroll
    for (int k = 0; k < 16; ++k) attS[h][k*64 + lane] = v[k] * rinv;
  }
  __syncthreads();
  // ---- iaw head-mean + u (4-way split-k over patch quarters) ----
  {
    float s = 0.f;
    #pragma unroll
    for (int h = 0; h < NH; ++h) s += attS[h][tid];
    iaw[(size_t)n*NP + tid] = s * 0.125f;
  }
  {
    const int ph = w >> 2, c = (w & 3)*64 + lane;
    float ua[NH];
    #pragma unroll
    for (int h = 0; h < NH; ++h) ua[h] = 0.f;
    const float* pb = patches + (size_t)ph*256*DD + c;
    #pragma unroll 2
    for (int pc = 0; pc < 64; ++pc) {
      float p0 = pb[(size_t)(pc*4+0)*DD];
      float p1 = pb[(size_t)(pc*4+1)*DD];
      float p2 = pb[(size_t)(pc*4+2)*DD];
      float p3 = pb[(size_t)(pc*4+3)*DD];
      #pragma unroll
      for (int h = 0; h < NH; ++h) {
        float4 a4 = *(const float4*)&attS[h][ph*256 + pc*4];
        ua[h] += a4.x*p0 + a4.y*p1 + a4.z*p2 + a4.w*p3;
      }
    }
    #pragma unroll
    for (int h = 0; h < NH; ++h) up[ph][h][c] = ua[h];
  }
  __syncthreads();
  if (tid < DD) {
    #pragma unroll
    for (int h = 0; h < NH; ++h)
      tS[h][tid] = up[0][h][tid] + up[1][h][tid] + up[2][h][tid] + up[3][h][tid];
  }
  __syncthreads();

  // ---- ctx = u @ Wv^T + bv (streams Wv) ----
  {
    float4 xf[8]; preload8(&tS[w >> 1][0], lane, xf);
    float a, b;
    pass16(Wn + (size_t)2*DD*DD, DD, w*16, lane, xf, &a, &b);
    int rA = w*16 + (lane >> 3);
    if ((lane & 7) == 0) { ctxL[rA] = a + bn[2*DD + rA]; ctxL[rA+8] = b + bn[2*DD + rA + 8]; }
  }
  __syncthreads();
  // ---- out = ctx @ Wo^T + bo + et (streams Wo); LN1 -> xL ----
  {
    float4 xf[8]; preload8(ctxL, lane, xf);
    const float* Won = Wo_e + (size_t)n*DD*DD;
    float a, b;
    pass16(Won, DD, w*16, lane, xf, &a, &b);
    int rA = w*16 + (lane >> 3);
    if ((lane & 7) == 0) {
      resS[rA]   = a + bo_e[(size_t)n*DD + rA]     + xL[rA];
      resS[rA+8] = b + bo_e[(size_t)n*DD + rA + 8] + xL[rA+8];
    }
  }
  layernorm_store(resS, xL, ln1g, ln1b, red2, tid, w, lane);
  __syncthreads();

  // ---- qca: q projection ----
  {
    float4 xf[8]; preload8(xL, lane, xf);
    float a, b;
    pass16(Wqkv_q, DD, w*16, lane, xf, &a, &b);
    int rA = w*16 + (lane >> 3);
    if ((lane & 7) == 0) { qL[rA] = a + bqkv_q[rA]; qL[rA+8] = b + bqkv_q[rA+8]; }
  }
  __syncthreads();
  // ---- qca: attention over 64 kv (waves 0-7) ----
  if (w < 8) {
    const int h = w, j = lane;
    float4 q4[8];
    #pragma unroll
    for (int m = 0; m < 8; ++m) q4[m] = *(const float4*)&qL[h*32 + 4*m];
    const float* kj = kvq + (size_t)j*512 + h*32;
    float s = 0.f;
    #pragma unroll
    for (int m = 0; m < 8; ++m) s += dot4(*(const float4*)&kj[4*m], q4[m]);
    s *= SCALE;
    float mx = wred_max(s);
    float p = __expf(s - mx);
    float sum = wred_sum(p);
    attq[h][j] = p / sum;
  }
  __syncthreads();
  if (tid < DD) {
    const int rr = tid, h = rr >> 5;
    float acc = 0.f;
    #pragma unroll 4
    for (int j4 = 0; j4 < 16; ++j4) {
      float4 a4 = *(const float4*)&attq[h][j4*4];
      acc += a4.x * kvq[(size_t)(j4*4+0)*512 + DD + rr]
           + a4.y * kvq[(size_t)(j4*4+1)*512 + DD + rr]
           + a4.z * kvq[(size_t)(j4*4+2)*512 + DD + rr]
           + a4.w * kvq[(size_t)(j4*4+3)*512 + DD + rr];
    }
    ctxL[rr] = acc;
  }
  __syncthreads();
  // ---- qca: out proj + residual; LN2 -> xL ----
  {
    float4 xf[8]; preload8(ctxL, lane, xf);
    float a, b;
    pass16(Wo_q, DD, w*16, lane, xf, &a, &b);
    int rA = w*16 + (lane >> 3);
    if ((lane & 7) == 0) { resS[rA] = a + bo_q[rA] + xL[rA]; resS[rA+8] = b + bo_q[rA+8] + xL[rA+8]; }
  }
  layernorm_store(resS, xL, ln2g, ln2b, red2, tid, w, lane);
  __syncthreads();

  // ---- FFN1 -> hb (aliases attS) ----
  {
    float4 xf[8]; preload8(xL, lane, xf);
    #pragma unroll
    for (int g = 0; g < 4; ++g) {
      int r0 = w*64 + g*16;
      float a, b;
      pass16(W1, DD, r0, lane, xf, &a, &b);
      int rA = r0 + (lane >> 3);
      if ((lane & 7) == 0) { hb[rA] = fmaxf(a + b1[rA], 0.f); hb[rA+8] = fmaxf(b + b1[rA+8], 0.f); }
    }
  }
  __syncthreads();
  // ---- FFN2 (K=1024 in 4 chunks) -> qL = expert_refined ----
  {
    float accA = 0.f, accB = 0.f;
    #pragma unroll
    for (int kc = 0; kc < 4; ++kc) {
      float4 xh[8]; preload8(hb + kc*256, lane, xh);
      float a, b;
      pass16(W2 + kc*256, 1024, w*16, lane, xh, &a, &b);
      accA += a; accB += b;
    }
    int rA = w*16 + (lane >> 3);
    if ((lane & 7) == 0) { qL[rA] = accA + b2[rA]; qL[rA+8] = accB + b2[rA+8]; }
  }
  __syncthreads();
  // ---- qkv_s projection (768 rows) -> qrow (aliases up) ----
  {
    float4 xf[8]; preload8(qL, lane, xf);
    #pragma unroll
    for (int g = 0; g < 3; ++g) {
      int r0 = w*48 + g*16;
      float a, b;
      pass16(Wqkv_s, DD, r0, lane, xf, &a, &b);
      int rA = r0 + (lane >> 3);
      if ((lane & 7) == 0) { qrow[rA] = a + bqkv_s[rA]; qrow[rA+8] = b + bqkv_s[rA+8]; }
    }
  }
  __syncthreads();
  if (tid < 768) qkvs_g[(size_t)n*768 + tid] = qrow[tid];
  if (tid < DD)  er_g[(size_t)n*DD + tid]   = qL[tid];
}

// ---------------- K3: self attention + LN3 ----------------
__global__ __launch_bounds__(1024)
void k_sa(const float* __restrict__ er, const float* __restrict__ qkvs,
          const float* __restrict__ Wo_s, const float* __restrict__ bo_s,
          const float* __restrict__ ln3g, const float* __restrict__ ln3b,
          float* __restrict__ ef)
{
  const int i = blockIdx.x, tid = threadIdx.x, w = tid >> 6, lane = tid & 63;
  __shared__ float x[DD], attl[NH][256], ctxp[4][DD], resS[DD], red2[2];
  if (tid < DD) x[tid] = er[(size_t)i*DD + tid];
  // scores: wave w -> head w&7, key-half w>>3
  {
    const int h = w & 7, kh = w >> 3;
    float4 q4[8];
    #pragma unroll
    for (int m = 0; m < 8; ++m) q4[m] = *(const float4*)&qkvs[(size_t)i*768 + h*32 + 4*m];
    #pragma unroll
    for (int rep = 0; rep < 2; ++rep) {
      int j = kh*128 + rep*64 + lane;
      const float* kj = qkvs + (size_t)j*768 + DD + h*32;
      float4 k4[8];
      #pragma unroll
      for (int m = 0; m < 8; ++m) k4[m] = *(const float4*)&kj[4*m];
      float s = 0.f;
      #pragma unroll
      for (int m = 0; m < 8; ++m) s += dot4(k4[m], q4[m]);
      attl[h][j] = s * SCALE;
    }
  }
  __syncthreads();
  if (w < 8) {
    const int h = w;
    float v0 = attl[h][lane], v1 = attl[h][lane+64], v2 = attl[h][lane+128], v3 = attl[h][lane+192];
    float mx = wred_max(fmaxf(fmaxf(v0,v1), fmaxf(v2,v3)));
    float e0 = __expf(v0-mx), e1 = __expf(v1-mx), e2 = __expf(v2-mx), e3 = __expf(v3-mx);
    float sum = wred_sum(e0+e1+e2+e3);
    float r = 1.f/sum;
    attl[h][lane] = e0*r; attl[h][lane+64] = e1*r; attl[h][lane+128] = e2*r; attl[h][lane+192] = e3*r;
  }
  __syncthreads();
  {
    const int rr = tid & 255, qtr = tid >> 8, h = rr >> 5;
    float acc = 0.f;
    #pragma unroll 4
    for (int j4 = qtr*16; j4 < qtr*16 + 16; ++j4) {
      float4 a4 = *(const float4*)&attl[h][j4*4];
      acc += a4.x * qkvs[(size_t)(j4*4+0)*768 + 512 + rr]
           + a4.y * qkvs[(size_t)(j4*4+1)*768 + 512 + rr]
           + a4.z * qkvs[(size_t)(j4*4+2)*768 + 512 + rr]
           + a4.w * qkvs[(size_t)(j4*4+3)*768 + 512 + rr];
    }
    ctxp[qtr][rr] = acc;
  }
  __syncthreads();
  {
    float4 xf[8];
    const int o = (lane & 7)*4;
    #pragma unroll
    for (int cc = 0; cc < 8; ++cc) {
      float4 a = *(const float4*)&ctxp[0][cc*32 + o];
      float4 b = *(const float4*)&ctxp[1][cc*32 + o];
      float4 c = *(const float4*)&ctxp[2][cc*32 + o];
      float4 d = *(const float4*)&ctxp[3][cc*32 + o];
      xf[cc] = make_float4(a.x+b.x+c.x+d.x, a.y+b.y+c.y+d.y,
                           a.z+b.z+c.z+d.z, a.w+b.w+c.w+d.w);
    }
    float a, b;
    pass16(Wo_s, DD, w*16, lane, xf, &a, &b);
    int rA = w*16 + (lane >> 3);
    if ((lane & 7) == 0) { resS[rA] = a + bo_s[rA] + x[rA]; resS[rA+8] = b + bo_s[rA+8] + x[rA+8]; }
  }
  layernorm_store(resS, ef + (size_t)i*DD, ln3g, ln3b, red2, tid, w, lane);
}

extern "C" void kernel_launch(void* const* d_in, const int* in_sizes, int n_in,
                              void* d_out, int out_size, void* d_ws, size_t ws_size,
                              hipStream_t stream) {
  const float* patches = (const float*)d_in[0];
  const float* et      = (const float*)d_in[1];
  const float* qe      = (const float*)d_in[2];
  const float* Wqkv_e  = (const float*)d_in[3];
  const float* bqkv_e  = (const float*)d_in[4];
  const float* Wo_e    = (const float*)d_in[5];
  const float* bo_e    = (const float*)d_in[6];
  const float* Wqkv_q  = (const float*)d_in[7];
  const float* bqkv_q  = (const float*)d_in[8];
  const float* Wo_q    = (const float*)d_in[9];
  const float* bo_q    = (const float*)d_in[10];
  const float* Wqkv_s  = (const float*)d_in[11];
  const float* bqkv_s  = (const float*)d_in[12];
  const float* Wo_s    = (const float*)d_in[13];
  const float* bo_s    = (const float*)d_in[14];
  const float* W1      = (const float*)d_in[15];
  const float* b1      = (const float*)d_in[16];
  const float* W2      = (const float*)d_in[17];
  const float* b2      = (const float*)d_in[18];
  const float* ln1g = (const float*)d_in[19]; const float* ln1b = (const float*)d_in[20];
  const float* ln2g = (const float*)d_in[21]; const float* ln2b = (const float*)d_in[22];
  const float* ln3g = (const float*)d_in[23]; const float* ln3b = (const float*)d_in[24];

  float* ef  = (float*)d_out;
  float* iaw = (float*)d_out + 65536;

  float* ws   = (float*)d_ws;
  float* pT   = ws;                   // 262144 floats
  float* kvq  = ws + 262144;          // 32768
  float* er   = ws + 294912;          // 65536
  float* qkvs = ws + 360448;          // 196608

  k_pre<<<320, 256, 0, stream>>>(patches, pT, qe, Wqkv_q, bqkv_q, kvq);
  k_expert<<<256, 1024, 0, stream>>>(patches, pT, et, Wqkv_e, bqkv_e, Wo_e, bo_e,
                                     kvq, Wqkv_q, bqkv_q, Wo_q, bo_q,
                                     W1, b1, W2, b2, Wqkv_s, bqkv_s,
                                     ln1g, ln1b, ln2g, ln2b,
                                     er, qkvs, iaw);
  k_sa<<<256, 1024, 0, stream>>>(er, qkvs, Wo_s, bo_s, ln3g, ln3b, ef);
}